// Round 3
// baseline (115.632 us; speedup 1.0000x reference)
//
#include <hip/hip_runtime.h>

// Shapes (fixed by the problem)
constexpr int TOK     = 1024 * 2048;  // B*S tokens
constexpr int TPB     = 256;          // threads per block
constexpr int TOK_PB  = 1024;         // tokens per block
constexpr int ITERS   = TOK_PB / TPB; // 4
constexpr int NBLK    = TOK / TOK_PB; // 2048 blocks

typedef float f32x4 __attribute__((ext_vector_type(4)));

// ws float layout (written by setup_fused):
// [0,32)      Gf[k=4][j=8]       = embed_w^T @ gate_w
// [32,40)     gb[8]              = embed_b @ gate_w
// [40,1064)   Wf[e=8][k=4][f=32] = embed_w^T @ wi[e]
// [1064,1320) ub[e=8][f=32]      = embed_b @ wi[e]
// [1320,2344) Pf[e=8][f=32][o=4] = wo[e] @ proj_w^T
// [2344,2348) pb[4]
constexpr int WS_FLOATS = 2348;

__global__ void setup_fused(
    const float* __restrict__ ew,  // [16][4]
    const float* __restrict__ eb,  // [16]
    const float* __restrict__ gw,  // [16][8]
    const float* __restrict__ wi,  // [8][16][32]
    const float* __restrict__ wo,  // [8][32][16]
    const float* __restrict__ pw,  // [4][16]
    const float* __restrict__ pb,  // [4]
    float* __restrict__ ws)
{
    int idx = blockIdx.x * blockDim.x + threadIdx.x;
    if (idx >= WS_FLOATS) return;
    float v = 0.0f;
    if (idx < 32) {
        int k = idx >> 3, j = idx & 7;
        for (int i = 0; i < 16; ++i) v += ew[i * 4 + k] * gw[i * 8 + j];
    } else if (idx < 40) {
        int j = idx - 32;
        for (int i = 0; i < 16; ++i) v += eb[i] * gw[i * 8 + j];
    } else if (idx < 1064) {
        int r = idx - 40; int e = r >> 7, k = (r >> 5) & 3, f = r & 31;
        for (int i = 0; i < 16; ++i) v += ew[i * 4 + k] * wi[(e * 16 + i) * 32 + f];
    } else if (idx < 1320) {
        int r = idx - 1064; int e = r >> 5, f = r & 31;
        for (int i = 0; i < 16; ++i) v += eb[i] * wi[(e * 16 + i) * 32 + f];
    } else if (idx < 2344) {
        int r = idx - 1320; int e = r >> 7, f = (r >> 2) & 31, o = r & 3;
        for (int i = 0; i < 16; ++i) v += wo[(e * 32 + f) * 16 + i] * pw[o * 16 + i];
    } else {
        v = pb[idx - 2344];
    }
    ws[idx] = v;
}

__device__ __forceinline__ f32x4 splat4(float s) { return (f32x4){s, s, s, s}; }

__global__ __launch_bounds__(256) void moe_main(
    const float* __restrict__ x,   // [T][4]
    const float* __restrict__ ws,  // fused weights (read-only here)
    float* __restrict__ out)       // [T][4]
{
    __shared__ float        s_p[TOK_PB];    // top_p per local token id
    __shared__ unsigned int s_sid[TOK_PB];  // sorted: (t_loc | e<<16)
    __shared__ int          s_cnt[8];
    __shared__ int          s_base[8];

    const int tid  = threadIdx.x;
    const int lane = tid & 63;
    const unsigned long long lt_mask = (lane == 63) ? 0x7fffffffffffffffull
                                                    : ((1ull << lane) - 1ull);

    if (tid < 8) s_cnt[tid] = 0;
    __syncthreads();

    const int gbase = blockIdx.x * TOK_PB;          // block's first token
    const f32x4* __restrict__ x4 = (const f32x4*)x;
    f32x4* __restrict__ o4       = (f32x4*)out;

    // Wave-uniform gate params (broadcast loads, hoisted; tiny).
    f32x4 Gr[8];
    #pragma unroll
    for (int q = 0; q < 8; ++q) Gr[q] = ((const f32x4*)ws)[q];
    const f32x4 w_gb0 = ((const f32x4*)ws)[8];
    const f32x4 w_gb1 = ((const f32x4*)ws)[9];
    const f32x4 w_pb  = ((const f32x4*)(ws + 2344))[0];

    constexpr float LOG2E  = 1.4426950408889634f;
    constexpr float GELU_K = 2.3025850929940457f;   // 2*0.7978845608*log2(e)
    constexpr float GELU_B = 0.044715f;
    const f32x4 one4 = splat4(1.0f);

    // ---------------- Pass 1: gate + counting-sort by expert ----------------
    int e_arr[ITERS], pos_arr[ITERS];

    #pragma unroll
    for (int it = 0; it < ITERS; ++it) {
        const int t_loc = it * TPB + tid;
        f32x4 xv = x4[gbase + t_loc];

        f32x4 ga = w_gb0, gb2 = w_gb1;
        #pragma unroll
        for (int k = 0; k < 4; ++k) {
            f32x4 xs = splat4(xv[k]);
            ga  = __builtin_elementwise_fma(xs, Gr[2 * k],     ga);
            gb2 = __builtin_elementwise_fma(xs, Gr[2 * k + 1], gb2);
        }
        float g[8] = {ga[0], ga[1], ga[2], ga[3], gb2[0], gb2[1], gb2[2], gb2[3]};

        float gmax = g[0]; int e = 0;
        #pragma unroll
        for (int j = 1; j < 8; ++j)
            if (g[j] > gmax) { gmax = g[j]; e = j; }
        float ssum = 0.0f;
        #pragma unroll
        for (int j = 0; j < 8; ++j)
            ssum += __builtin_amdgcn_exp2f((g[j] - gmax) * LOG2E);
        s_p[t_loc] = __builtin_amdgcn_rcpf(ssum);   // top_p

        // wave-aggregated counting: 8 ballots, 8 atomics per wave
        int pos_w = 0, my_cnt = 0;
        #pragma unroll
        for (int j = 0; j < 8; ++j) {
            unsigned long long bj = __ballot(e == j);
            int pc_lt = __popcll(bj & lt_mask);
            int pc    = __popcll(bj);
            if (e == j)    pos_w  = pc_lt;
            if (lane == j) my_cnt = pc;
        }
        int base_w = 0;
        if (lane < 8) base_w = atomicAdd(&s_cnt[lane], my_cnt);
        int base = __shfl(base_w, e, 64);           // base for MY expert
        e_arr[it]   = e;
        pos_arr[it] = base + pos_w;
    }
    __syncthreads();

    if (tid == 0) {
        int run = 0;
        #pragma unroll
        for (int j = 0; j < 8; ++j) { s_base[j] = run; run += s_cnt[j]; }
    }
    __syncthreads();

    #pragma unroll
    for (int it = 0; it < ITERS; ++it) {
        const int t_loc = it * TPB + tid;
        const int slot  = s_base[e_arr[it]] + pos_arr[it];
        s_sid[slot] = (unsigned)t_loc | ((unsigned)e_arr[it] << 16);
    }
    __syncthreads();

    // ---------------- Pass 2: expert-sorted compute ----------------
    #pragma unroll 1
    for (int it = 0; it < ITERS; ++it) {
        const unsigned v  = s_sid[it * TPB + tid];
        const int sid  = (int)(v & 0xffffu);
        const int eTok = (int)(v >> 16);

        f32x4 xv = x4[gbase + sid];
        float tp = s_p[sid];

        bool done = false;
        while (true) {
            unsigned long long act = __ballot(!done);
            if (act == 0) break;
            int src = (int)__builtin_ctzll(act);
            int e0  = __shfl(eTok, src, 64);
            e0 = __builtin_amdgcn_readfirstlane(e0);

            if (!done && eTok == e0) {
                const f32x4* __restrict__ wf4 = (const f32x4*)(ws + 40   + e0 * 128);
                const f32x4* __restrict__ ub4 = (const f32x4*)(ws + 1064 + e0 * 32);
                const f32x4* __restrict__ pf4 = (const f32x4*)(ws + 1320 + e0 * 128);

                f32x4 U[8];
                #pragma unroll
                for (int q = 0; q < 8; ++q) U[q] = ub4[q];
                #pragma unroll
                for (int k = 0; k < 4; ++k) {
                    f32x4 xs = splat4(xv[k]);
                    #pragma unroll
                    for (int q = 0; q < 8; ++q)
                        U[q] = __builtin_elementwise_fma(xs, wf4[k * 8 + q], U[q]);
                }

                // gelu (tanh form, NaN-safe): v - v/(1+t), t = 2^(K*v*(1+b*v^2))
                #pragma unroll
                for (int q = 0; q < 8; ++q) {
                    f32x4 vv = U[q];
                    f32x4 m  = __builtin_elementwise_fma(vv * splat4(GELU_B), vv, one4);
                    f32x4 a  = (vv * splat4(GELU_K)) * m;
                    f32x4 tt;
                    #pragma unroll
                    for (int c = 0; c < 4; ++c) tt[c] = __builtin_amdgcn_exp2f(a[c]);
                    tt = tt + one4;
                    f32x4 r;
                    #pragma unroll
                    for (int c = 0; c < 4; ++c) r[c] = __builtin_amdgcn_rcpf(tt[c]);
                    U[q] = __builtin_elementwise_fma(-vv, r, vv);
                }

                f32x4 acc = splat4(0.0f);
                #pragma unroll
                for (int q = 0; q < 8; ++q) {
                    #pragma unroll
                    for (int c = 0; c < 4; ++c)
                        acc = __builtin_elementwise_fma(splat4(U[q][c]), pf4[q * 4 + c], acc);
                }
                o4[gbase + sid] = __builtin_elementwise_fma(splat4(tp), acc, w_pb);
                done = true;
            }
        }
    }
}

extern "C" void kernel_launch(void* const* d_in, const int* in_sizes, int n_in,
                              void* d_out, int out_size, void* d_ws, size_t ws_size,
                              hipStream_t stream) {
    const float* x  = (const float*)d_in[0];
    const float* ew = (const float*)d_in[1];
    const float* eb = (const float*)d_in[2];
    const float* gw = (const float*)d_in[3];
    const float* wi = (const float*)d_in[4];
    const float* wo = (const float*)d_in[5];
    const float* pw = (const float*)d_in[6];
    const float* pb = (const float*)d_in[7];
    float* ws  = (float*)d_ws;
    float* out = (float*)d_out;

    setup_fused<<<(WS_FLOATS + 255) / 256, 256, 0, stream>>>(ew, eb, gw, wi, wo, pw, pb, ws);
    moe_main<<<NBLK, TPB, 0, stream>>>(x, ws, out);
}

// Round 4
// 50.108 us; speedup vs baseline: 2.3077x; 2.3077x over previous
//
#include <hip/hip_runtime.h>

// Shapes (fixed by the problem)
constexpr int TOK     = 1024 * 2048;  // B*S tokens
constexpr int TPB     = 256;          // threads per block
constexpr int TOK_PB  = 1024;         // tokens per block
constexpr int ITERS   = TOK_PB / TPB; // 4
constexpr int NBLK    = TOK / TOK_PB; // 2048 blocks

typedef float f32x4 __attribute__((ext_vector_type(4)));

// ws float layout (written by setup_fused):
// [0,32)      Gf[k=4][j=8]       = embed_w^T @ gate_w
// [32,40)     gb[8]              = embed_b @ gate_w
// [40,1064)   Wf[e=8][k=4][f=32] = embed_w^T @ wi[e]
// [1064,1320) ub[e=8][f=32]      = embed_b @ wi[e]
// [1320,2344) Pf[e=8][f=32][o=4] = wo[e] @ proj_w^T
// [2344,2348) pb[4]
constexpr int WS_FLOATS = 2348;

__global__ void setup_fused(
    const float* __restrict__ ew,  // [16][4]
    const float* __restrict__ eb,  // [16]
    const float* __restrict__ gw,  // [16][8]
    const float* __restrict__ wi,  // [8][16][32]
    const float* __restrict__ wo,  // [8][32][16]
    const float* __restrict__ pw,  // [4][16]
    const float* __restrict__ pb,  // [4]
    float* __restrict__ ws)
{
    int idx = blockIdx.x * blockDim.x + threadIdx.x;
    if (idx >= WS_FLOATS) return;
    float v = 0.0f;
    if (idx < 32) {
        int k = idx >> 3, j = idx & 7;
        for (int i = 0; i < 16; ++i) v += ew[i * 4 + k] * gw[i * 8 + j];
    } else if (idx < 40) {
        int j = idx - 32;
        for (int i = 0; i < 16; ++i) v += eb[i] * gw[i * 8 + j];
    } else if (idx < 1064) {
        int r = idx - 40; int e = r >> 7, k = (r >> 5) & 3, f = r & 31;
        for (int i = 0; i < 16; ++i) v += ew[i * 4 + k] * wi[(e * 16 + i) * 32 + f];
    } else if (idx < 1320) {
        int r = idx - 1064; int e = r >> 5, f = r & 31;
        for (int i = 0; i < 16; ++i) v += eb[i] * wi[(e * 16 + i) * 32 + f];
    } else if (idx < 2344) {
        int r = idx - 1320; int e = r >> 7, f = (r >> 2) & 31, o = r & 3;
        for (int i = 0; i < 16; ++i) v += wo[(e * 32 + f) * 16 + i] * pw[o * 16 + i];
    } else {
        v = pb[idx - 2344];
    }
    ws[idx] = v;
}

__device__ __forceinline__ f32x4 splat4(float s) { return (f32x4){s, s, s, s}; }

__global__ __launch_bounds__(256) void moe_main(
    const float* __restrict__ x,   // [T][4]
    const float* __restrict__ ws,  // fused weights
    float* __restrict__ out)       // [T][4]
{
    __shared__ __align__(16) f32x4 s_x[TOK_PB];          // x stash -> result
    __shared__ float           s_p[TOK_PB];              // top_p per token
    __shared__ unsigned short  s_sid[TOK_PB];            // sorted: sid | e<<10
    __shared__ int             s_cnt[8];
    __shared__ int             s_base[8];
    __shared__ __align__(16) float sWf[8 * 128];
    __shared__ __align__(16) float sUb[8 * 32];
    __shared__ __align__(16) float sPf[8 * 128];

    const int tid  = threadIdx.x;
    const int lane = tid & 63;
    const unsigned long long lt_mask = (lane == 63) ? 0x7fffffffffffffffull
                                                    : ((1ull << lane) - 1ull);

    if (tid < 8) s_cnt[tid] = 0;
    // Stage fused weights to LDS (coalesced, once per block).
    {
        int i = tid;
        #pragma unroll
        for (int rep = 0; rep < 4; ++rep, i += 256) {
            sWf[i] = ws[40 + i];
            sPf[i] = ws[1320 + i];
        }
        sUb[tid] = ws[1064 + tid];
    }

    const int gbase = blockIdx.x * TOK_PB;
    const f32x4* __restrict__ x4 = (const f32x4*)x;
    f32x4* __restrict__ o4       = (f32x4*)out;

    // Wave-uniform gate/proj params from global (scalar broadcast loads).
    f32x4 Gr[8];
    #pragma unroll
    for (int q = 0; q < 8; ++q) Gr[q] = ((const f32x4*)ws)[q];
    const f32x4 w_gb0 = ((const f32x4*)ws)[8];
    const f32x4 w_gb1 = ((const f32x4*)ws)[9];
    const f32x4 w_pb  = ((const f32x4*)(ws + 2344))[0];

    constexpr float LOG2E  = 1.4426950408889634f;
    constexpr float GELU_K = 2.3025850929940457f;   // 2*0.7978845608*log2(e)
    constexpr float GELU_B = 0.044715f;
    const f32x4 one4 = splat4(1.0f);

    __syncthreads();   // s_cnt zeroed (weights not needed until pass 2)

    // ---------------- Pass 1: gate + stash + counting-sort ----------------
    int e_arr[ITERS], pos_arr[ITERS];

    #pragma unroll
    for (int it = 0; it < ITERS; ++it) {
        const int t_loc = it * TPB + tid;
        f32x4 xv = x4[gbase + t_loc];
        s_x[t_loc] = xv;

        f32x4 ga = w_gb0, gb2 = w_gb1;
        #pragma unroll
        for (int k = 0; k < 4; ++k) {
            f32x4 xs = splat4(xv[k]);
            ga  = __builtin_elementwise_fma(xs, Gr[2 * k],     ga);
            gb2 = __builtin_elementwise_fma(xs, Gr[2 * k + 1], gb2);
        }
        float g[8] = {ga[0], ga[1], ga[2], ga[3], gb2[0], gb2[1], gb2[2], gb2[3]};

        float gmax = g[0]; int e = 0;
        #pragma unroll
        for (int j = 1; j < 8; ++j)
            if (g[j] > gmax) { gmax = g[j]; e = j; }
        float ssum = 0.0f;
        #pragma unroll
        for (int j = 0; j < 8; ++j)
            ssum += __builtin_amdgcn_exp2f((g[j] - gmax) * LOG2E);
        s_p[t_loc] = __builtin_amdgcn_rcpf(ssum);

        // wave-aggregated counting: 8 ballots, 8 atomics per wave
        int pos_w = 0, my_cnt = 0;
        #pragma unroll
        for (int j = 0; j < 8; ++j) {
            unsigned long long bj = __ballot(e == j);
            int pc_lt = __popcll(bj & lt_mask);
            int pc    = __popcll(bj);
            if (e == j)    pos_w  = pc_lt;
            if (lane == j) my_cnt = pc;
        }
        int base_w = 0;
        if (lane < 8) base_w = atomicAdd(&s_cnt[lane], my_cnt);
        int base = __shfl(base_w, e, 64);
        e_arr[it]   = e;
        pos_arr[it] = base + pos_w;
    }
    __syncthreads();

    if (tid == 0) {
        int run = 0;
        #pragma unroll
        for (int j = 0; j < 8; ++j) { s_base[j] = run; run += s_cnt[j]; }
    }
    __syncthreads();

    #pragma unroll
    for (int it = 0; it < ITERS; ++it) {
        const int t_loc = it * TPB + tid;
        const int slot  = s_base[e_arr[it]] + pos_arr[it];
        s_sid[slot] = (unsigned short)(t_loc | (e_arr[it] << 10));
    }
    __syncthreads();

    // ------- Pass 2: sorted order -> near-uniform expert, LDS broadcast -----
    #pragma unroll 1
    for (int it = 0; it < ITERS; ++it) {
        const unsigned v = s_sid[it * TPB + tid];
        const int sid = (int)(v & 1023u);
        const int e   = (int)(v >> 10);

        f32x4 xv = s_x[sid];
        float tp = s_p[sid];

        const f32x4* __restrict__ wf4 = (const f32x4*)(sWf + e * 128);
        const f32x4* __restrict__ ub4 = (const f32x4*)(sUb + e * 32);
        const f32x4* __restrict__ pf4 = (const f32x4*)(sPf + e * 128);

        f32x4 U[8];
        #pragma unroll
        for (int q = 0; q < 8; ++q) U[q] = ub4[q];
        #pragma unroll
        for (int k = 0; k < 4; ++k) {
            f32x4 xs = splat4(xv[k]);
            #pragma unroll
            for (int q = 0; q < 8; ++q)
                U[q] = __builtin_elementwise_fma(xs, wf4[k * 8 + q], U[q]);
        }

        // gelu (tanh form, NaN-safe): v - v/(1+t), t = 2^(K*v*(1+b*v^2))
        #pragma unroll
        for (int q = 0; q < 8; ++q) {
            f32x4 vv = U[q];
            f32x4 m  = __builtin_elementwise_fma(vv * splat4(GELU_B), vv, one4);
            f32x4 a  = (vv * splat4(GELU_K)) * m;
            f32x4 tt;
            #pragma unroll
            for (int c = 0; c < 4; ++c) tt[c] = __builtin_amdgcn_exp2f(a[c]);
            tt = tt + one4;
            f32x4 r;
            #pragma unroll
            for (int c = 0; c < 4; ++c) r[c] = __builtin_amdgcn_rcpf(tt[c]);
            U[q] = __builtin_elementwise_fma(-vv, r, vv);
        }

        f32x4 acc = splat4(0.0f);
        #pragma unroll
        for (int q = 0; q < 8; ++q) {
            #pragma unroll
            for (int c = 0; c < 4; ++c)
                acc = __builtin_elementwise_fma(splat4(U[q][c]), pf4[q * 4 + c], acc);
        }
        // write result back to own slot (each token touched by exactly one thread)
        s_x[sid] = __builtin_elementwise_fma(splat4(tp), acc, w_pb);
    }
    __syncthreads();

    // ---------------- Pass 3: coalesced writeback ----------------
    #pragma unroll
    for (int it = 0; it < ITERS; ++it) {
        const int t_loc = it * TPB + tid;
        o4[gbase + t_loc] = s_x[t_loc];
    }
}

extern "C" void kernel_launch(void* const* d_in, const int* in_sizes, int n_in,
                              void* d_out, int out_size, void* d_ws, size_t ws_size,
                              hipStream_t stream) {
    const float* x  = (const float*)d_in[0];
    const float* ew = (const float*)d_in[1];
    const float* eb = (const float*)d_in[2];
    const float* gw = (const float*)d_in[3];
    const float* wi = (const float*)d_in[4];
    const float* wo = (const float*)d_in[5];
    const float* pw = (const float*)d_in[6];
    const float* pb = (const float*)d_in[7];
    float* ws  = (float*)d_ws;
    float* out = (float*)d_out;

    setup_fused<<<(WS_FLOATS + 255) / 256, 256, 0, stream>>>(ew, eb, gw, wi, wo, pw, pb, ws);
    moe_main<<<NBLK, TPB, 0, stream>>>(x, ws, out);
}